// Round 1
// baseline (117.825 us; speedup 1.0000x reference)
//
#include <hip/hip_runtime.h>
#include <math.h>

// Soft-label cross-entropy, mean reduction.
// input, target: [N, C] float32, C=40 (160 B rows, float4-aligned).
// out: scalar float32.

#define THREADS 256
#define BLOCKS  2048   // 524288 threads -> exactly 4 rows/thread at N=2M

__global__ __launch_bounds__(THREADS) void ce_partial(
    const float* __restrict__ input,
    const float* __restrict__ target,
    float* __restrict__ partials, int N)
{
    const int tid    = blockIdx.x * blockDim.x + threadIdx.x;
    const int stride = gridDim.x * blockDim.x;

    float acc = 0.f;
    for (int row = tid; row < N; row += stride) {
        const float4* xin = reinterpret_cast<const float4*>(input  + (size_t)row * 40);
        const float4* tin = reinterpret_cast<const float4*>(target + (size_t)row * 40);

        float4 x[10];
        #pragma unroll
        for (int j = 0; j < 10; ++j) x[j] = xin[j];

        float m = x[0].x;
        #pragma unroll
        for (int j = 0; j < 10; ++j)
            m = fmaxf(m, fmaxf(fmaxf(x[j].x, x[j].y), fmaxf(x[j].z, x[j].w)));

        float se = 0.f, dot = 0.f, ts = 0.f;
        #pragma unroll
        for (int j = 0; j < 10; ++j) {
            float4 t = tin[j];
            se  += __expf(x[j].x - m) + __expf(x[j].y - m)
                 + __expf(x[j].z - m) + __expf(x[j].w - m);
            dot += t.x * x[j].x + t.y * x[j].y + t.z * x[j].z + t.w * x[j].w;
            ts  += t.x + t.y + t.z + t.w;
        }
        const float lse = m + __logf(se);
        // loss_i = -sum_c t_c * (x_c - lse) = ts*lse - dot
        acc += ts * lse - dot;
    }

    // wave reduce (64 lanes)
    #pragma unroll
    for (int off = 32; off > 0; off >>= 1) acc += __shfl_down(acc, off, 64);

    __shared__ float sdata[THREADS / 64];
    const int lane = threadIdx.x & 63, wid = threadIdx.x >> 6;
    if (lane == 0) sdata[wid] = acc;
    __syncthreads();
    if (threadIdx.x == 0) {
        float s = 0.f;
        #pragma unroll
        for (int w = 0; w < THREADS / 64; ++w) s += sdata[w];
        partials[blockIdx.x] = s;
    }
}

__global__ __launch_bounds__(256) void ce_final(
    const float* __restrict__ partials, float* __restrict__ out,
    int nPartials, float invN)
{
    float acc = 0.f;
    for (int i = threadIdx.x; i < nPartials; i += blockDim.x) acc += partials[i];

    #pragma unroll
    for (int off = 32; off > 0; off >>= 1) acc += __shfl_down(acc, off, 64);

    __shared__ float sdata[4];
    const int lane = threadIdx.x & 63, wid = threadIdx.x >> 6;
    if (lane == 0) sdata[wid] = acc;
    __syncthreads();
    if (threadIdx.x == 0) {
        out[0] = (sdata[0] + sdata[1] + sdata[2] + sdata[3]) * invN;
    }
}

extern "C" void kernel_launch(void* const* d_in, const int* in_sizes, int n_in,
                              void* d_out, int out_size, void* d_ws, size_t ws_size,
                              hipStream_t stream)
{
    const float* input  = (const float*)d_in[0];
    const float* target = (const float*)d_in[1];
    float* out = (float*)d_out;
    float* partials = (float*)d_ws;   // BLOCKS floats = 8 KB

    const int C = 40;
    const int N = in_sizes[0] / C;    // 2097152

    ce_partial<<<BLOCKS, THREADS, 0, stream>>>(input, target, partials, N);
    ce_final<<<1, 256, 0, stream>>>(partials, out, BLOCKS, 1.0f / (float)N);
}